// Round 3
// baseline (366.903 us; speedup 1.0000x reference)
//
#include <hip/hip_runtime.h>
#include <stdint.h>
#include <math.h>

// Native vector types — __builtin_nontemporal_{load,store} requires a native
// vector, not HIP's float4 class.
typedef float vf4 __attribute__((ext_vector_type(4)));
typedef float vf2 __attribute__((ext_vector_type(2)));

__device__ __forceinline__ void mm4(vf4 v, float& mn, float& mx) {
    mn = fminf(mn, fminf(fminf(v.x, v.y), fminf(v.z, v.w)));
    mx = fmaxf(mx, fmaxf(fmaxf(v.x, v.y), fmaxf(v.z, v.w)));
}

__device__ __forceinline__ vf4 q4(vf4 v, float mn, float scale, float inv_scale) {
    vf4 r;
    r.x = rintf((v.x - mn) * scale) * inv_scale + mn;
    r.y = rintf((v.y - mn) * scale) * inv_scale + mn;
    r.z = rintf((v.z - mn) * scale) * inv_scale + mn;
    r.w = rintf((v.w - mn) * scale) * inv_scale + mn;
    return r;
}

// ---------------------------------------------------------------------------
// Pass 1: per-block min/max -> plain 8 B store of {min,max} into ws[bid].
// No atomics, no init kernel. The kernel boundary is the global barrier
// (round-1 lesson: cg grid.sync() costs ~200 µs at 2048 blocks).
//
// Round-3 fix: the old cleanup loop strode by bs only, so after the 6.125
// super-iterations at grid=2048 every block b<256 redundantly walked the
// whole 4 MB tail in serial 16 B steps (~30-50 µs straggler, invisible in
// FETCH_SIZE because the re-reads hit L3). Now: counted main loop
// (niter = n4/chunk) + flat grid-strided tail (<=1 iter/thread). The host
// picks grid=1792 so this shape divides exactly (1792*1024*7 == n4): zero
// tail, perfect balance.
// ---------------------------------------------------------------------------
__global__ __launch_bounds__(256) void minmax_partial(
    const float* __restrict__ x, long n,
    vf2* __restrict__ ws)
{
    const vf4* __restrict__ x4 = (const vf4*)x;
    const unsigned n4 = (unsigned)(n >> 2);

    float mn0 = INFINITY, mn1 = INFINITY, mn2 = INFINITY, mn3 = INFINITY;
    float mx0 = -INFINITY, mx1 = -INFINITY, mx2 = -INFINITY, mx3 = -INFINITY;

    const unsigned bs  = blockDim.x;                 // 256
    const unsigned tid = threadIdx.x;
    const unsigned chunk = gridDim.x * bs * 4u;      // vf4 per super-iteration
    const unsigned niter = n4 / chunk;

    // 4x unroll, independent accumulators: 4 x 16 B loads in flight per
    // thread per iteration; disjoint dest registers keep them outstanding.
    unsigned base = blockIdx.x * bs * 4u + tid;
    for (unsigned k = 0; k < niter; ++k, base += chunk) {
        vf4 v0 = x4[base];
        vf4 v1 = x4[base + bs];
        vf4 v2 = x4[base + 2u * bs];
        vf4 v3 = x4[base + 3u * bs];
        mm4(v0, mn0, mx0);
        mm4(v1, mn1, mx1);
        mm4(v2, mn2, mx2);
        mm4(v3, mn3, mx3);
    }
    // Grid-strided vf4 tail: <= 1 iteration per thread when tail < chunk.
    for (unsigned idx = niter * chunk + blockIdx.x * bs + tid; idx < n4;
         idx += gridDim.x * bs)
        mm4(x4[idx], mn0, mx0);
    // Scalar tail (n % 4 != 0) — not hit for this shape, kept for generality.
    for (long i = (long)n4 * 4 + (long)blockIdx.x * bs + tid; i < n;
         i += (long)gridDim.x * bs) {
        float v = x[i];
        mn0 = fminf(mn0, v); mx0 = fmaxf(mx0, v);
    }

    float mn = fminf(fminf(mn0, mn1), fminf(mn2, mn3));
    float mx = fmaxf(fmaxf(mx0, mx1), fmaxf(mx2, mx3));
    #pragma unroll
    for (int off = 32; off > 0; off >>= 1) {
        mn = fminf(mn, __shfl_down(mn, off, 64));
        mx = fmaxf(mx, __shfl_down(mx, off, 64));
    }
    __shared__ float smn[4], smx[4];
    const int wave = tid >> 6;
    const int lane = tid & 63;
    if (lane == 0) { smn[wave] = mn; smx[wave] = mx; }
    __syncthreads();
    if (tid == 0) {
        vf2 p;
        p.x = fminf(fminf(smn[0], smn[1]), fminf(smn[2], smn[3]));
        p.y = fmaxf(fmaxf(smx[0], smx[1]), fmaxf(smx[2], smx[3]));
        ws[blockIdx.x] = p;   // plain store; kernel-end flush makes it visible
    }
}

// ---------------------------------------------------------------------------
// Pass 2: every block redundantly reduces the nb partials (nb*8 B = 14 KB,
// L2/L3-resident after pass 1 — ~1-2 µs), then quantizes its chunk.
// NT stores: output is written once and never re-read; bypassing the caches
// keeps the input (L3-hot from pass 1) from being evicted by write-allocate
// (verified round 1: FETCH_SIZE == 1x input for the two passes combined).
// Same counted-main-loop + grid-strided-tail fix as pass 1.
// ---------------------------------------------------------------------------
__global__ __launch_bounds__(256) void quant_from_partials(
    const float* __restrict__ x, long n,
    float* __restrict__ o,
    const vf2* __restrict__ ws, unsigned nb)
{
    const vf4* __restrict__ x4 = (const vf4*)x;
    vf4* __restrict__ o4 = (vf4*)o;
    const unsigned n4 = (unsigned)(n >> 2);
    const unsigned bs  = blockDim.x;
    const unsigned tid = threadIdx.x;

    // --- preamble: global min/max from partials ---
    float mn = INFINITY, mx = -INFINITY;
    for (unsigned i = tid; i < nb; i += bs) {
        vf2 p = ws[i];
        mn = fminf(mn, p.x);
        mx = fmaxf(mx, p.y);
    }
    #pragma unroll
    for (int off = 32; off > 0; off >>= 1) {
        mn = fminf(mn, __shfl_down(mn, off, 64));
        mx = fmaxf(mx, __shfl_down(mx, off, 64));
    }
    __shared__ float smn[4], smx[4];
    const int wave = tid >> 6;
    const int lane = tid & 63;
    if (lane == 0) { smn[wave] = mn; smx[wave] = mx; }
    __syncthreads();
    const float fmn = fminf(fminf(smn[0], smn[1]), fminf(smn[2], smn[3]));
    const float fmx = fmaxf(fmaxf(smx[0], smx[1]), fmaxf(smx[2], smx[3]));
    const float scale = 255.0f / (fmx - fmn);
    const float inv_scale = 1.0f / scale;

    // --- main quant loop (counted; zero tail at grid=1792 for this shape) ---
    const unsigned chunk = gridDim.x * bs * 4u;
    const unsigned niter = n4 / chunk;
    unsigned base = blockIdx.x * bs * 4u + tid;
    for (unsigned k = 0; k < niter; ++k, base += chunk) {
        vf4 v0 = x4[base];
        vf4 v1 = x4[base + bs];
        vf4 v2 = x4[base + 2u * bs];
        vf4 v3 = x4[base + 3u * bs];
        __builtin_nontemporal_store(q4(v0, fmn, scale, inv_scale), &o4[base]);
        __builtin_nontemporal_store(q4(v1, fmn, scale, inv_scale), &o4[base + bs]);
        __builtin_nontemporal_store(q4(v2, fmn, scale, inv_scale), &o4[base + 2u * bs]);
        __builtin_nontemporal_store(q4(v3, fmn, scale, inv_scale), &o4[base + 3u * bs]);
    }
    // Grid-strided vf4 tail: <= 1 iteration per thread, no redundant writes.
    for (unsigned idx = niter * chunk + blockIdx.x * bs + tid; idx < n4;
         idx += gridDim.x * bs)
        __builtin_nontemporal_store(q4(x4[idx], fmn, scale, inv_scale), &o4[idx]);
    // Scalar tail (n % 4 != 0) — not hit for this shape.
    for (long i = (long)n4 * 4 + (long)blockIdx.x * bs + tid; i < n;
         i += (long)gridDim.x * bs)
        o[i] = rintf((x[i] - fmn) * scale) * inv_scale + fmn;
}

extern "C" void kernel_launch(void* const* d_in, const int* in_sizes, int n_in,
                              void* d_out, int out_size, void* d_ws, size_t ws_size,
                              hipStream_t stream) {
    const float* x = (const float*)d_in[0];
    float* out = (float*)d_out;
    const long n = (long)in_sizes[0];

    const int block = 256;
    // grid=1792: n4 = 2^18*49 vf4; per-block super-iteration = 1024 vf4;
    // 1792*1024*7 == n4 exactly -> 7 full iterations, zero tail, perfect
    // load balance. 1792 blocks = 7/CU = 28 waves/CU. Partials = 14 KB.
    int grid = 1792;
    if (ws_size < (size_t)grid * sizeof(vf2)) {
        size_t g = ws_size / sizeof(vf2);
        grid = (g < 256) ? 256 : (int)g;
    }

    vf2* ws = (vf2*)d_ws;
    minmax_partial<<<grid, block, 0, stream>>>(x, n, ws);
    quant_from_partials<<<grid, block, 0, stream>>>(x, n, out, ws, (unsigned)grid);
}